// Round 13
// baseline (208.623 us; speedup 1.0000x reference)
//
#include <hip/hip_runtime.h>
#include <hip/hip_bf16.h>

// Problem constants
#define B_ 2
#define S_ 2048
#define DM_ 1024
#define TD_ 1024
#define H_ 16
#define HD_ 64

using bf16 = __hip_bfloat16;
typedef __attribute__((ext_vector_type(8))) short s8v;   // 8 bf16 = one MFMA A/B frag
typedef __attribute__((ext_vector_type(4))) float f4v;   // MFMA C/D frag

__device__ __forceinline__ f4v mfma_bf16(s8v a, s8v b, f4v c) {
    return __builtin_amdgcn_mfma_f32_16x16x32_bf16(a, b, c, 0, 0, 0);
}

// HW packed fp32x2 -> bf16x2 (RNE), single VOP3 instr on CDNA3/4
__device__ __forceinline__ unsigned cvt_pk_bf16(float a, float b) {
    unsigned r;
    asm("v_cvt_pk_bf16_f32 %0, %1, %2" : "=v"(r) : "v"(a), "v"(b));
    return r;
}
__device__ __forceinline__ int2 pack4bf(float a, float b, float c, float d) {
    int2 r;
    r.x = (int)cvt_pk_bf16(a, b);
    r.y = (int)cvt_pk_bf16(c, d);
    return r;
}

// cos_q[0] == 1.0 exactly: fp32 word = 0x3F800000 (low16==0); bf16 pair != 0 low16.
__device__ __forceinline__ bool detect_f32(const unsigned int* __restrict__ cosw) {
    return (cosw[0] & 0xFFFFu) == 0u;
}

// load 4 consecutive floats from dual-dtype table (idx multiple of 4)
__device__ __forceinline__ void ld4_f(const void* p, int idx, bool f32, float* o) {
    if (f32) {
        float4 v = *reinterpret_cast<const float4*>((const float*)p + idx);
        o[0] = v.x; o[1] = v.y; o[2] = v.z; o[3] = v.w;
    } else {
        const bf16* q = (const bf16*)p + idx;
        #pragma unroll
        for (int i = 0; i < 4; i++) o[i] = __bfloat162float(q[i]);
    }
}

// async global -> LDS, 16 B per lane (HW: dst = wave-uniform base + lane*16)
__device__ __forceinline__ void gload_lds16(const bf16* g, void* l) {
    __builtin_amdgcn_global_load_lds(
        (const __attribute__((address_space(1))) unsigned int*)(const void*)g,
        (__attribute__((address_space(3))) unsigned int*)l,
        16, 0, 0);
}

#define NQ_  (B_ * S_ * DM_)
#define NWI_ (3 * TD_ * DM_)
#define NWO_ (DM_ * TD_)
#define NCVT_BLOCKS ((NQ_ + NWI_ + NWO_) / 2048)   // 4096

// ---------------------------------------------------------------------------
// Fused prep: blocks [0,4096) convert (query|W_in|W_out) -> bf16;
// blocks 4096..4097 compute lengths[b] from the mask (4-way storage detect).
// ---------------------------------------------------------------------------
__global__ __launch_bounds__(256)
void prep_all(const void* __restrict__ q, const void* __restrict__ wi,
              const void* __restrict__ wo, bf16* __restrict__ dst,
              const void* __restrict__ mask, int* __restrict__ lengths,
              const unsigned int* __restrict__ cosw) {
    const int bid = blockIdx.x;
    if (bid < NCVT_BLOCKS) {
        const bool f32 = detect_f32(cosw);
        int i = (bid * 256 + threadIdx.x) * 8;
        const void* src; int off;
        if (i < NQ_)              { src = q;  off = i; }
        else if (i < NQ_ + NWI_)  { src = wi; off = i - NQ_; }
        else                      { src = wo; off = i - NQ_ - NWI_; }
        if (f32) {
            const float* p = (const float*)src + off;
            float4 x = *reinterpret_cast<const float4*>(p);
            float4 y = *reinterpret_cast<const float4*>(p + 4);
            union { unsigned u[4]; int4 v; } t;
            t.u[0] = cvt_pk_bf16(x.x, x.y);
            t.u[1] = cvt_pk_bf16(x.z, x.w);
            t.u[2] = cvt_pk_bf16(y.x, y.y);
            t.u[3] = cvt_pk_bf16(y.z, y.w);
            *reinterpret_cast<int4*>(dst + i) = t.v;
        } else {
            *reinterpret_cast<int4*>(dst + i) =
                *reinterpret_cast<const int4*>((const bf16*)src + off);
        }
        return;
    }
    // lengths path
    int b = bid - NCVT_BLOCKS;
    unsigned int w0 = ((const unsigned int*)mask)[0];
    int enc;                 // 0=i32, 1=u8, 2=bf16, 3=f32
    if (w0 == 1u) enc = 0;
    else if (w0 == 0x01010101u) enc = 1;
    else if (w0 == 0x3F803F80u) enc = 2;
    else enc = 3;
    int cnt = 0;
    for (int s = threadIdx.x; s < S_; s += 256) {
        int i = b * S_ + s;
        bool v;
        if (enc == 0)      v = ((const int*)mask)[i] != 0;
        else if (enc == 1) v = ((const unsigned char*)mask)[i] != 0;
        else if (enc == 2) v = ((const unsigned short*)mask)[i] != 0;
        else               v = ((const float*)mask)[i] != 0.f;
        cnt += v ? 1 : 0;
    }
    __shared__ int red[256];
    red[threadIdx.x] = cnt;
    __syncthreads();
    for (int off = 128; off > 0; off >>= 1) {
        if (threadIdx.x < off) red[threadIdx.x] += red[threadIdx.x + off];
        __syncthreads();
    }
    if (threadIdx.x == 0) lengths[b] = red[0];
}

// ---------------------------------------------------------------------------
// NT GEMM: C[M][N] = A[M][K]*Bm[N][K]^T. bf16 in, fp32 acc. BK=64,
// global_load_lds width-16, XOR-swizzled LDS, swapped-operand MFMA.
// mode 0: bf16 C write.  mode 1: detected-dtype C write (fp32 if inputs fp32).
// mode 2: FUSED QKV epilogue — RoPE(Q)->Qh (scaled log2e/8), RoPE(K)->Kt
// (tiled+swizzled), V->Vtmp[m][1024] plain. Rotate-half partner of
// acc[mb][nb] is acc[mb][nb^2] (same lane) since a wave's 64 cols = one head.
// ---------------------------------------------------------------------------
__global__ __launch_bounds__(256)
void gemm_nt(const bf16* __restrict__ A, const bf16* __restrict__ Bm,
             void* __restrict__ C, int M, int N, int K, int mode,
             const void* __restrict__ sin_t, const void* __restrict__ cos_t,
             bf16* __restrict__ Qh, bf16* __restrict__ Kt,
             bf16* __restrict__ Vtmp, const unsigned int* __restrict__ cosw) {
    __shared__ bf16 lds_a[128 * 64];   // 16 KB, [row][chunk^(row&7)]
    __shared__ bf16 lds_b[128 * 64];

    const int t = threadIdx.x;
    const int wave = t >> 6, lane = t & 63;
    const int quad = lane >> 4, l16 = lane & 15;
    const int wm = wave >> 1, wn = wave & 1;
    const int m0 = blockIdx.y * 128, n0 = blockIdx.x * 128;
    const int wuni = __builtin_amdgcn_readfirstlane(wave);   // wave-uniform

    f4v acc[4][4];
    #pragma unroll
    for (int i = 0; i < 4; i++)
        #pragma unroll
        for (int j = 0; j < 4; j++)
            acc[i][j] = f4v{0.f, 0.f, 0.f, 0.f};

    for (int k0 = 0; k0 < K; k0 += 64) {
        __syncthreads();                 // prior reads done before restage
        #pragma unroll
        for (int i = 0; i < 4; i++) {
            int ci = i * 256 + t;        // chunk 0..1023 (16B each)
            int row = ci >> 3;
            int csrc = (ci & 7) ^ (row & 7);
            gload_lds16(A + (size_t)(m0 + row) * K + k0 + csrc * 8,
                        (char*)lds_a + i * 4096 + wuni * 1024);
            gload_lds16(Bm + (size_t)(n0 + row) * K + k0 + csrc * 8,
                        (char*)lds_b + i * 4096 + wuni * 1024);
        }
        __syncthreads();                 // drains vmcnt -> staged data visible

        #pragma unroll
        for (int kk = 0; kk < 2; kk++) {
            s8v afr[4], bfr[4];
            #pragma unroll
            for (int mb = 0; mb < 4; mb++) {
                int r = wm * 64 + mb * 16 + l16;
                int ch = (kk * 4 + quad) ^ (l16 & 7);
                afr[mb] = *reinterpret_cast<const s8v*>(&lds_a[r * 64 + ch * 8]);
            }
            #pragma unroll
            for (int nb = 0; nb < 4; nb++) {
                int r = wn * 64 + nb * 16 + l16;
                int ch = (kk * 4 + quad) ^ (l16 & 7);
                bfr[nb] = *reinterpret_cast<const s8v*>(&lds_b[r * 64 + ch * 8]);
            }
            // swapped: D[i=n-in-16][j=m-in-16], lane j=l16, regs i=quad*4+rr
            #pragma unroll
            for (int mb = 0; mb < 4; mb++)
                #pragma unroll
                for (int nb = 0; nb < 4; nb++)
                    acc[mb][nb] = mfma_bf16(bfr[nb], afr[mb], acc[mb][nb]);
        }
    }

    if (mode == 2) {
        const bool f32 = detect_f32(cosw);
        const int nc = n0 + wn * 64;          // wave's 64-col window
        const int region = nc >> 10;          // 0=Q, 1=K, 2=V
        const int h = (nc >> 6) & 15;
        #pragma unroll
        for (int mb = 0; mb < 4; mb++) {
            int m = m0 + wm * 64 + mb * 16 + l16;
            int s = m & (S_ - 1), bb = m >> 11;
            if (region == 2) {
                #pragma unroll
                for (int nb = 0; nb < 4; nb++) {
                    int vcol = (nc - 2048) + nb * 16 + quad * 4;
                    f4v v = acc[mb][nb];
                    *reinterpret_cast<int2*>(&Vtmp[(size_t)m * 1024 + vcol]) =
                        pack4bf(v[0], v[1], v[2], v[3]);
                }
            } else {
                #pragma unroll
                for (int nb = 0; nb < 4; nb++) {
                    int d0 = nb * 16 + quad * 4;
                    float cs[4], sn[4];
                    ld4_f(cos_t, s * 64 + d0, f32, cs);
                    ld4_f(sin_t, s * 64 + d0, f32, sn);
                    float sgn = (nb < 2) ? -1.f : 1.f;
                    float ov[4];
                    #pragma unroll
                    for (int rr = 0; rr < 4; rr++)
                        ov[rr] = acc[mb][nb][rr] * cs[rr] +
                                 sgn * acc[mb][nb ^ 2][rr] * sn[rr];
                    if (region == 0) {
                        #pragma unroll
                        for (int rr = 0; rr < 4; rr++) ov[rr] *= 0.180336880f; // log2e/8
                        size_t o = (((size_t)(bb * 16 + h)) * S_ + s) * 64 + d0;
                        *reinterpret_cast<int2*>(&Qh[o]) =
                            pack4bf(ov[0], ov[1], ov[2], ov[3]);
                    } else {
                        size_t ktile = ((size_t)(bb * 16 + h) * 32 + (s >> 6)) * 4096;
                        int chunk = (d0 >> 3) ^ (s & 7);
                        size_t o = ktile + (s & 63) * 64 + chunk * 8 + (d0 & 7);
                        *reinterpret_cast<int2*>(&Kt[o]) =
                            pack4bf(ov[0], ov[1], ov[2], ov[3]);
                    }
                }
            }
        }
        return;
    }

    // mode 0/1 epilogue: m per lane, 4 consecutive n per acc reg
    const bool cf32 = (mode == 1) && detect_f32(cosw);
    #pragma unroll
    for (int mb = 0; mb < 4; mb++) {
        int m = m0 + wm * 64 + mb * 16 + l16;
        #pragma unroll
        for (int nb = 0; nb < 4; nb++) {
            int n = n0 + wn * 64 + nb * 16 + quad * 4;
            f4v v = acc[mb][nb];
            if (cf32) {
                *reinterpret_cast<f4v*>(&((float*)C)[(size_t)m * N + n]) = v;
            } else {
                *reinterpret_cast<int2*>(&((bf16*)C)[(size_t)m * N + n]) =
                    pack4bf(v[0], v[1], v[2], v[3]);
            }
        }
    }
}

// ---------------------------------------------------------------------------
// V transpose: Vtmp [m][1024] -> Vt tiled+swizzled [d][keychunk^(d&7)].
// Grid 1024: one 64x64 tile per block.
// ---------------------------------------------------------------------------
__global__ __launch_bounds__(256)
void v_transpose(const bf16* __restrict__ Vtmp, bf16* __restrict__ Vt) {
    __shared__ bf16 tile[64 * 72];     // [s][d] pad 72
    const int vid = blockIdx.x;        // 0..1023
    const int sb = vid & 31, h = (vid >> 5) & 15, b = vid >> 9;
    const int t = threadIdx.x;
    #pragma unroll
    for (int i = 0; i < 2; i++) {
        int id = i * 256 + t;          // 0..511
        int row = id >> 3, c = id & 7;
        *reinterpret_cast<int4*>(&tile[row * 72 + c * 8]) =
            *reinterpret_cast<const int4*>(
                Vtmp + (size_t)(b * S_ + sb * 64 + row) * 1024 + h * 64 + c * 8);
    }
    __syncthreads();
    const size_t tb = ((size_t)(b * H_ + h) * 32 + sb) * 4096;
    #pragma unroll
    for (int i = 0; i < 2; i++) {
        int id = i * 256 + t;
        int d = id >> 3, kc = id & 7;  // kc = 8-key chunk
        union { short s[8]; int4 v; } u;
        #pragma unroll
        for (int e = 0; e < 8; e++)
            u.s[e] = reinterpret_cast<const short*>(tile)[(kc * 8 + e) * 72 + d];
        *reinterpret_cast<int4*>(Vt + tb + d * 64 + ((kc ^ (d & 7)) * 8)) = u.v;
    }
}

// ---------------------------------------------------------------------------
// Flash attention (r12 structure): 512-thread blocks (8 waves). Waves 0-3 own
// q-tile 2g, waves 4-7 own 2g+1; K/V staged once per block, shared. Per-wave
// depth-2 pipeline: S[kt]; exp/pack/PV[kt-1]; wave-local lgkm P round trip.
// ---------------------------------------------------------------------------
__global__ __launch_bounds__(512)
void attn_fused(const bf16* __restrict__ Qh, const bf16* __restrict__ Kt,
                const bf16* __restrict__ Vt, const int* __restrict__ lengths,
                bf16* __restrict__ out) {
    __shared__ bf16 k_buf[2 * 4096];   // dbuf K tiles  (16 KB)
    __shared__ bf16 v_buf[2 * 4096];   // dbuf V tiles  (16 KB)
    __shared__ bf16 lds_p[8 * 16 * 72];// per-wave P regions (18 KB)

    const int t = threadIdx.x, wave = t >> 6, lane = t & 63;
    const int quad = lane >> 4, l16 = lane & 15;
    const int grp = wave >> 2;          // 0 -> qb=2g, 1 -> qb=2g+1
    const int wq = wave & 3;            // wave-in-group -> 16-row band

    const int bid = blockIdx.x;
    const int xcd = bid & 7;
    int g, bh;
    if (bid < 256) {
        int r = bid >> 3;               // 0..31
        bh = xcd * 4 + (r & 3);
        g = r >> 2;                     // 0..7
    } else {
        int r = (bid - 256) >> 3;
        bh = xcd * 4 + (r & 3);
        g = 15 - (r >> 2);              // 15..8
    }
    const int qb = 2 * g + grp;
    const int b = bh >> 4, h = bh & 15;

    const size_t hb = (size_t)bh * S_ * 64;          // Qh base
    const bf16* Ktp = Kt + (size_t)bh * 32 * 4096;   // tile array base
    const bf16* Vtp = Vt + (size_t)bh * 32 * 4096;
    const int wuni = __builtin_amdgcn_readfirstlane(wave);
    int len_raw = lengths[b];
    const int len_b = len_raw < 1 ? 1 : (len_raw > S_ ? S_ : len_raw);
    const int nkt_len = (len_b + 63) >> 6;

    const int nkt_w = (qb + 1) < nkt_len ? (qb + 1) : nkt_len;      // wave span
    const int nkt   = (2 * g + 2) < nkt_len ? (2 * g + 2) : nkt_len;// block span

    const int qrow_g = qb * 64 + wq * 16 + l16;      // this lane's q-row
    const int kmax = (qrow_g < len_b - 1) ? qrow_g : (len_b - 1);

    s8v qf[2];
    {
        const bf16* qptr = Qh + hb + (size_t)qrow_g * 64 + quad * 8;
        qf[0] = *reinterpret_cast<const s8v*>(qptr);
        qf[1] = *reinterpret_cast<const s8v*>(qptr + 32);
    }

    f4v o_acc[4];
    #pragma unroll
    for (int a = 0; a < 4; a++) o_acc[a] = f4v{0.f, 0.f, 0.f, 0.f};
    float l_sum = 0.f;

    auto stageK = [&](int x) {
        gload_lds16(Ktp + (size_t)x * 4096 + t * 8,
                    (char*)k_buf + (x & 1) * 8192 + wuni * 1024);
    };
    auto stageV = [&](int x) {
        gload_lds16(Vtp + (size_t)x * 4096 + t * 8,
                    (char*)v_buf + (x & 1) * 8192 + wuni * 1024);
    };

    f4v s_prev[4];
    auto process_tile = [&](int pt) {
        const bf16* vb = v_buf + (pt & 1) * 4096;
        const int pbase = pt * 64;
        const bool tail = (pt == qb) || (pbase + 64 > len_b);  // wave-uniform
        #pragma unroll
        for (int a = 0; a < 4; a++) {
            float e0[4];
            #pragma unroll
            for (int r = 0; r < 4; r++) {
                float e = __builtin_amdgcn_exp2f(s_prev[a][r]);
                if (tail) {
                    int key = pbase + a * 16 + quad * 4 + r;
                    e = (key <= kmax) ? e : 0.f;
                }
                e0[r] = e;
                l_sum += e;
            }
            *reinterpret_cast<int2*>(
                &lds_p[(wave * 16 + l16) * 72 + a * 16 + quad * 4]) =
                pack4bf(e0[0], e0[1], e0[2], e0[3]);
        }
        asm volatile("s_waitcnt lgkmcnt(0)" ::: "memory");
        #pragma unroll
        for (int kk = 0; kk < 2; kk++) {
            s8v pf = *reinterpret_cast<const s8v*>(
                &lds_p[(wave * 16 + l16) * 72 + kk * 32 + quad * 8]);
            #pragma unroll
            for (int a = 0; a < 4; a++) {
                int ch = (kk * 4 + quad) ^ (l16 & 7);
                s8v vf = *reinterpret_cast<const s8v*>(
                    &vb[(a * 16 + l16) * 64 + ch * 8]);
                o_acc[a] = mfma_bf16(vf, pf, o_acc[a]);
            }
        }
    };

    stageK(0);
    __syncthreads();   // K[0] resident (drains vmcnt)

    for (int kt = 0; kt < nkt; kt++) {
        stageV(kt);
        if (kt + 1 < nkt) stageK(kt + 1);

        const bool act = (kt < nkt_w);
        f4v sn[4];
        if (act) {
            const bf16* kb = k_buf + (kt & 1) * 4096;
            #pragma unroll
            for (int a = 0; a < 4; a++) sn[a] = f4v{0.f, 0.f, 0.f, 0.f};
            #pragma unroll
            for (int kk = 0; kk < 2; kk++) {
                #pragma unroll
                for (int a = 0; a < 4; a++) {
                    int ch = (kk * 4 + quad) ^ (l16 & 7);
                    s8v kf = *reinterpret_cast<const s8v*>(
                        &kb[(a * 16 + l16) * 64 + ch * 8]);
                    sn[a] = mfma_bf16(kf, qf[kk], sn[a]);
                }
            }
        }

        if (kt >= 1 && (kt - 1) < nkt_w) process_tile(kt - 1);

        if (act) {
            #pragma unroll
            for (int a = 0; a < 4; a++) s_prev[a] = sn[a];
        }

        __syncthreads();   // staged tiles resident; slot reads complete
    }
    if (nkt_w == nkt) process_tile(nkt_w - 1);

    l_sum += __shfl_xor(l_sum, 16);
    l_sum += __shfl_xor(l_sum, 32);
    float inv_l = 1.f / l_sum;
    size_t orow = ((size_t)(b * S_ + qrow_g)) * TD_ + h * 64;
    #pragma unroll
    for (int a = 0; a < 4; a++) {
        *reinterpret_cast<int2*>(&out[orow + a * 16 + quad * 4]) =
            pack4bf(o_acc[a][0] * inv_l, o_acc[a][1] * inv_l,
                    o_acc[a][2] * inv_l, o_acc[a][3] * inv_l);
    }
}

// ---------------------------------------------------------------------------
extern "C" void kernel_launch(void* const* d_in, const int* in_sizes, int n_in,
                              void* d_out, int out_size, void* d_ws, size_t ws_size,
                              hipStream_t stream) {
    const void* query = d_in[0];   // [B,S,DM]  fp32 (auto-detected, bf16-safe)
    const void* W_in  = d_in[1];   // [3TD,DM]
    const void* W_out = d_in[2];   // [DM,TD]
    const void* sin_q = d_in[3];   // [S,HD]
    const void* cos_q = d_in[4];   // [S,HD]   dtype probe
    const void* mask  = d_in[5];   // [B,S] bool, storage auto-detected
    const unsigned int* cosw = (const unsigned int*)cos_q;

    const size_t nQ  = NQ_;   // 4194304
    const size_t nWi = NWI_;  // 3145728
    const size_t nWo = NWO_;  // 1048576

    bf16* Vtmp = (bf16*)d_ws;                 // [4096,1024]; later attn out
    bf16* Qh   = Vtmp + nQ;
    bf16* Kt   = Qh + nQ;                     // tiled+swizzled K
    bf16* qbf  = Kt + nQ;                     // query bf16; later Vt tiles
    bf16* wibf = qbf + nQ;
    bf16* wobf = wibf + nWi;
    int* lengths = (int*)(wobf + nWo);
    bf16* Vt   = qbf;    // alias: qbf dead after gemm1
    bf16* attn = Vtmp;   // alias: Vtmp dead after v_transpose

    prep_all<<<NCVT_BLOCKS + B_, 256, 0, stream>>>(
        query, W_in, W_out, qbf, mask, lengths, cosw);

    // gemm1 with fused RoPE epilogue: writes Qh, Kt (swizzled), Vtmp
    dim3 g1(3072 / 128, 4096 / 128);
    gemm_nt<<<g1, 256, 0, stream>>>(qbf, wibf, nullptr, 4096, 3072, 1024, 2,
                                    sin_q, cos_q, Qh, Kt, Vtmp, cosw);

    v_transpose<<<1024, 256, 0, stream>>>(Vtmp, Vt);

    attn_fused<<<512, 512, 0, stream>>>(Qh, Kt, Vt, lengths, attn);

    dim3 g2(1024 / 128, 4096 / 128);
    gemm_nt<<<g2, 256, 0, stream>>>(attn, wobf, d_out, 4096, 1024, 1024, 1,
                                    nullptr, nullptr, nullptr, nullptr, nullptr, cosw);
}

// Round 14
// 204.014 us; speedup vs baseline: 1.0226x; 1.0226x over previous
//
#include <hip/hip_runtime.h>
#include <hip/hip_bf16.h>

// Problem constants
#define B_ 2
#define S_ 2048
#define DM_ 1024
#define TD_ 1024
#define H_ 16
#define HD_ 64

using bf16 = __hip_bfloat16;
typedef __attribute__((ext_vector_type(8))) short s8v;   // 8 bf16 = one MFMA A/B frag
typedef __attribute__((ext_vector_type(4))) float f4v;   // MFMA C/D frag

__device__ __forceinline__ f4v mfma_bf16(s8v a, s8v b, f4v c) {
    return __builtin_amdgcn_mfma_f32_16x16x32_bf16(a, b, c, 0, 0, 0);
}

// HW packed fp32x2 -> bf16x2 (RNE), single VOP3 instr on CDNA3/4
__device__ __forceinline__ unsigned cvt_pk_bf16(float a, float b) {
    unsigned r;
    asm("v_cvt_pk_bf16_f32 %0, %1, %2" : "=v"(r) : "v"(a), "v"(b));
    return r;
}
__device__ __forceinline__ int2 pack4bf(float a, float b, float c, float d) {
    int2 r;
    r.x = (int)cvt_pk_bf16(a, b);
    r.y = (int)cvt_pk_bf16(c, d);
    return r;
}
// unpack int2 (4 bf16) -> 4 floats
__device__ __forceinline__ void unpack4bf(int2 v, float* o) {
    union { unsigned u; float f; } t;
    t.u = ((unsigned)v.x) << 16;          o[0] = t.f;
    t.u = ((unsigned)v.x) & 0xFFFF0000u;  o[1] = t.f;
    t.u = ((unsigned)v.y) << 16;          o[2] = t.f;
    t.u = ((unsigned)v.y) & 0xFFFF0000u;  o[3] = t.f;
}

// cos_q[0] == 1.0 exactly: fp32 word = 0x3F800000 (low16==0); bf16 pair != 0 low16.
__device__ __forceinline__ bool detect_f32(const unsigned int* __restrict__ cosw) {
    return (cosw[0] & 0xFFFFu) == 0u;
}

// async global -> LDS, 16 B per lane (HW: dst = wave-uniform base + lane*16)
__device__ __forceinline__ void gload_lds16(const bf16* g, void* l) {
    __builtin_amdgcn_global_load_lds(
        (const __attribute__((address_space(1))) unsigned int*)(const void*)g,
        (__attribute__((address_space(3))) unsigned int*)l,
        16, 0, 0);
}

#define NQ_  (B_ * S_ * DM_)
#define NWI_ (3 * TD_ * DM_)
#define NWO_ (DM_ * TD_)
#define NCVT_BLOCKS ((NQ_ + NWI_ + NWO_) / 2048)   // 4096
#define NTAB_BLOCKS 64                             // 2 x [S][32] bf16 tables

// ---------------------------------------------------------------------------
// Fused prep: [0,4096) cvt (query|W_in|W_out) -> bf16; [4096,4160) build
// bf16 cos/sin [S][32] tables; last B_ blocks compute lengths from the mask.
// ---------------------------------------------------------------------------
__global__ __launch_bounds__(256)
void prep_all(const void* __restrict__ q, const void* __restrict__ wi,
              const void* __restrict__ wo, bf16* __restrict__ dst,
              const void* __restrict__ sin_t, const void* __restrict__ cos_t,
              bf16* __restrict__ cosb, bf16* __restrict__ sinb,
              const void* __restrict__ mask, int* __restrict__ lengths) {
    const unsigned int* cosw = (const unsigned int*)cos_t;
    const int bid = blockIdx.x;
    if (bid < NCVT_BLOCKS) {
        const bool f32 = detect_f32(cosw);
        int i = (bid * 256 + threadIdx.x) * 8;
        const void* src; int off;
        if (i < NQ_)              { src = q;  off = i; }
        else if (i < NQ_ + NWI_)  { src = wi; off = i - NQ_; }
        else                      { src = wo; off = i - NQ_ - NWI_; }
        if (f32) {
            const float* p = (const float*)src + off;
            float4 x = *reinterpret_cast<const float4*>(p);
            float4 y = *reinterpret_cast<const float4*>(p + 4);
            union { unsigned u[4]; int4 v; } t;
            t.u[0] = cvt_pk_bf16(x.x, x.y);
            t.u[1] = cvt_pk_bf16(x.z, x.w);
            t.u[2] = cvt_pk_bf16(y.x, y.y);
            t.u[3] = cvt_pk_bf16(y.z, y.w);
            *reinterpret_cast<int4*>(dst + i) = t.v;
        } else {
            *reinterpret_cast<int4*>(dst + i) =
                *reinterpret_cast<const int4*>((const bf16*)src + off);
        }
        return;
    }
    if (bid < NCVT_BLOCKS + NTAB_BLOCKS) {
        // tables: combined space [cos | sin], each S_*32 elems
        const bool f32 = detect_f32(cosw);
        int e = ((bid - NCVT_BLOCKS) * 256 + threadIdx.x) * 8;  // 0..131064
        int tbl = e >> 16;                 // 0 = cos, 1 = sin
        int pos = e & 65535;
        int s = pos >> 5, j = pos & 31;    // 8 consecutive j within a row
        const void* src = tbl ? sin_t : cos_t;
        bf16* d = (tbl ? sinb : cosb) + pos;
        int si = s * 64 + j;
        if (f32) {
            const float* p = (const float*)src + si;
            float4 x = *reinterpret_cast<const float4*>(p);
            float4 y = *reinterpret_cast<const float4*>(p + 4);
            union { unsigned u[4]; int4 v; } t;
            t.u[0] = cvt_pk_bf16(x.x, x.y);
            t.u[1] = cvt_pk_bf16(x.z, x.w);
            t.u[2] = cvt_pk_bf16(y.x, y.y);
            t.u[3] = cvt_pk_bf16(y.z, y.w);
            *reinterpret_cast<int4*>(d) = t.v;
        } else {
            *reinterpret_cast<int4*>(d) =
                *reinterpret_cast<const int4*>((const bf16*)src + si);
        }
        return;
    }
    // lengths path
    int b = bid - NCVT_BLOCKS - NTAB_BLOCKS;
    unsigned int w0 = ((const unsigned int*)mask)[0];
    int enc;                 // 0=i32, 1=u8, 2=bf16, 3=f32
    if (w0 == 1u) enc = 0;
    else if (w0 == 0x01010101u) enc = 1;
    else if (w0 == 0x3F803F80u) enc = 2;
    else enc = 3;
    int cnt = 0;
    for (int s = threadIdx.x; s < S_; s += 256) {
        int i = b * S_ + s;
        bool v;
        if (enc == 0)      v = ((const int*)mask)[i] != 0;
        else if (enc == 1) v = ((const unsigned char*)mask)[i] != 0;
        else if (enc == 2) v = ((const unsigned short*)mask)[i] != 0;
        else               v = ((const float*)mask)[i] != 0.f;
        cnt += v ? 1 : 0;
    }
    __shared__ int red[256];
    red[threadIdx.x] = cnt;
    __syncthreads();
    for (int off = 128; off > 0; off >>= 1) {
        if (threadIdx.x < off) red[threadIdx.x] += red[threadIdx.x + off];
        __syncthreads();
    }
    if (threadIdx.x == 0) lengths[b] = red[0];
}

// ---------------------------------------------------------------------------
// NT GEMM: C[M][N] = A[M][K]*Bm[N][K]^T. bf16 in, fp32 acc. BK=64,
// global_load_lds width-16, XOR-swizzled LDS, swapped-operand MFMA.
// mode 0: bf16 C. mode 1: detected-dtype C. mode 2: fused QKV epilogue —
// RoPE via LDS-staged bf16 cos/sin [128][36] (reusing lds_a/lds_b after the
// K-loop; 2-way-max bank pattern), Q->Qh (scaled log2e/8), K->Kt swizzled,
// V->Vtmp. Rotate partner acc[mb][nb^2] is lane-local.
// ---------------------------------------------------------------------------
__global__ __launch_bounds__(256)
void gemm_nt(const bf16* __restrict__ A, const bf16* __restrict__ Bm,
             void* __restrict__ C, int M, int N, int K, int mode,
             const bf16* __restrict__ cosb, const bf16* __restrict__ sinb,
             bf16* __restrict__ Qh, bf16* __restrict__ Kt,
             bf16* __restrict__ Vtmp, const unsigned int* __restrict__ cosw) {
    __shared__ bf16 lds_a[128 * 64];   // 16 KB, [row][chunk^(row&7)]
    __shared__ bf16 lds_b[128 * 64];

    const int t = threadIdx.x;
    const int wave = t >> 6, lane = t & 63;
    const int quad = lane >> 4, l16 = lane & 15;
    const int wm = wave >> 1, wn = wave & 1;
    const int m0 = blockIdx.y * 128, n0 = blockIdx.x * 128;
    const int wuni = __builtin_amdgcn_readfirstlane(wave);   // wave-uniform

    f4v acc[4][4];
    #pragma unroll
    for (int i = 0; i < 4; i++)
        #pragma unroll
        for (int j = 0; j < 4; j++)
            acc[i][j] = f4v{0.f, 0.f, 0.f, 0.f};

    for (int k0 = 0; k0 < K; k0 += 64) {
        __syncthreads();                 // prior reads done before restage
        #pragma unroll
        for (int i = 0; i < 4; i++) {
            int ci = i * 256 + t;        // chunk 0..1023 (16B each)
            int row = ci >> 3;
            int csrc = (ci & 7) ^ (row & 7);
            gload_lds16(A + (size_t)(m0 + row) * K + k0 + csrc * 8,
                        (char*)lds_a + i * 4096 + wuni * 1024);
            gload_lds16(Bm + (size_t)(n0 + row) * K + k0 + csrc * 8,
                        (char*)lds_b + i * 4096 + wuni * 1024);
        }
        __syncthreads();                 // drains vmcnt -> staged data visible

        #pragma unroll
        for (int kk = 0; kk < 2; kk++) {
            s8v afr[4], bfr[4];
            #pragma unroll
            for (int mb = 0; mb < 4; mb++) {
                int r = wm * 64 + mb * 16 + l16;
                int ch = (kk * 4 + quad) ^ (l16 & 7);
                afr[mb] = *reinterpret_cast<const s8v*>(&lds_a[r * 64 + ch * 8]);
            }
            #pragma unroll
            for (int nb = 0; nb < 4; nb++) {
                int r = wn * 64 + nb * 16 + l16;
                int ch = (kk * 4 + quad) ^ (l16 & 7);
                bfr[nb] = *reinterpret_cast<const s8v*>(&lds_b[r * 64 + ch * 8]);
            }
            // swapped: D[i=n-in-16][j=m-in-16], lane j=l16, regs i=quad*4+rr
            #pragma unroll
            for (int mb = 0; mb < 4; mb++)
                #pragma unroll
                for (int nb = 0; nb < 4; nb++)
                    acc[mb][nb] = mfma_bf16(bfr[nb], afr[mb], acc[mb][nb]);
        }
    }

    if (mode == 2) {
        const int nc = n0 + wn * 64;          // wave's 64-col window
        const int region = nc >> 10;          // 0=Q, 1=K, 2=V
        const int h = (nc >> 6) & 15;
        const int s0 = m0 & (S_ - 1);         // block's 128 rows: one b, contiguous s

        // restage cos/sin rows [128][32] -> padded [128][36] in lds_a/lds_b
        __syncthreads();                      // K-loop LDS reads complete
        #pragma unroll
        for (int i = 0; i < 2; i++) {
            int e = (i * 256 + t) * 8;        // 0..4088, 8 cols within a row
            int row = e >> 5, col = e & 31;
            *reinterpret_cast<int4*>(&lds_a[row * 36 + col]) =
                *reinterpret_cast<const int4*>(cosb + (size_t)(s0 + row) * 32 + col);
            *reinterpret_cast<int4*>(&lds_b[row * 36 + col]) =
                *reinterpret_cast<const int4*>(sinb + (size_t)(s0 + row) * 32 + col);
        }
        __syncthreads();

        #pragma unroll
        for (int mb = 0; mb < 4; mb++) {
            int mrow = wm * 64 + mb * 16 + l16;   // row within block
            int m = m0 + mrow;
            int s = m & (S_ - 1), bb = m >> 11;
            if (region == 2) {
                #pragma unroll
                for (int nb = 0; nb < 4; nb++) {
                    int vcol = (nc - 2048) + nb * 16 + quad * 4;
                    f4v v = acc[mb][nb];
                    *reinterpret_cast<int2*>(&Vtmp[(size_t)m * 1024 + vcol]) =
                        pack4bf(v[0], v[1], v[2], v[3]);
                }
            } else {
                #pragma unroll
                for (int nb = 0; nb < 4; nb++) {
                    int d0 = nb * 16 + quad * 4;
                    int cidx = d0 & 31;
                    float cs[4], sn[4];
                    unpack4bf(*reinterpret_cast<const int2*>(&lds_a[mrow * 36 + cidx]), cs);
                    unpack4bf(*reinterpret_cast<const int2*>(&lds_b[mrow * 36 + cidx]), sn);
                    float sgn = (nb < 2) ? -1.f : 1.f;
                    float ov[4];
                    #pragma unroll
                    for (int rr = 0; rr < 4; rr++)
                        ov[rr] = acc[mb][nb][rr] * cs[rr] +
                                 sgn * acc[mb][nb ^ 2][rr] * sn[rr];
                    if (region == 0) {
                        #pragma unroll
                        for (int rr = 0; rr < 4; rr++) ov[rr] *= 0.180336880f; // log2e/8
                        size_t o = (((size_t)(bb * 16 + h)) * S_ + s) * 64 + d0;
                        *reinterpret_cast<int2*>(&Qh[o]) =
                            pack4bf(ov[0], ov[1], ov[2], ov[3]);
                    } else {
                        size_t ktile = ((size_t)(bb * 16 + h) * 32 + (s >> 6)) * 4096;
                        int chunk = (d0 >> 3) ^ (s & 7);
                        size_t o = ktile + (s & 63) * 64 + chunk * 8 + (d0 & 7);
                        *reinterpret_cast<int2*>(&Kt[o]) =
                            pack4bf(ov[0], ov[1], ov[2], ov[3]);
                    }
                }
            }
        }
        return;
    }

    // mode 0/1 epilogue: m per lane, 4 consecutive n per acc reg
    const bool cf32 = (mode == 1) && detect_f32(cosw);
    #pragma unroll
    for (int mb = 0; mb < 4; mb++) {
        int m = m0 + wm * 64 + mb * 16 + l16;
        #pragma unroll
        for (int nb = 0; nb < 4; nb++) {
            int n = n0 + wn * 64 + nb * 16 + quad * 4;
            f4v v = acc[mb][nb];
            if (cf32) {
                *reinterpret_cast<f4v*>(&((float*)C)[(size_t)m * N + n]) = v;
            } else {
                *reinterpret_cast<int2*>(&((bf16*)C)[(size_t)m * N + n]) =
                    pack4bf(v[0], v[1], v[2], v[3]);
            }
        }
    }
}

// ---------------------------------------------------------------------------
// V transpose: Vtmp [m][1024] -> Vt tiled+swizzled [d][keychunk^(d&7)].
// ---------------------------------------------------------------------------
__global__ __launch_bounds__(256)
void v_transpose(const bf16* __restrict__ Vtmp, bf16* __restrict__ Vt) {
    __shared__ bf16 tile[64 * 72];     // [s][d] pad 72
    const int vid = blockIdx.x;        // 0..1023
    const int sb = vid & 31, h = (vid >> 5) & 15, b = vid >> 9;
    const int t = threadIdx.x;
    #pragma unroll
    for (int i = 0; i < 2; i++) {
        int id = i * 256 + t;          // 0..511
        int row = id >> 3, c = id & 7;
        *reinterpret_cast<int4*>(&tile[row * 72 + c * 8]) =
            *reinterpret_cast<const int4*>(
                Vtmp + (size_t)(b * S_ + sb * 64 + row) * 1024 + h * 64 + c * 8);
    }
    __syncthreads();
    const size_t tb = ((size_t)(b * H_ + h) * 32 + sb) * 4096;
    #pragma unroll
    for (int i = 0; i < 2; i++) {
        int id = i * 256 + t;
        int d = id >> 3, kc = id & 7;  // kc = 8-key chunk
        union { short s[8]; int4 v; } u;
        #pragma unroll
        for (int e = 0; e < 8; e++)
            u.s[e] = reinterpret_cast<const short*>(tile)[(kc * 8 + e) * 72 + d];
        *reinterpret_cast<int4*>(Vt + tb + d * 64 + ((kc ^ (d & 7)) * 8)) = u.v;
    }
}

// ---------------------------------------------------------------------------
// Flash attention (r12 structure): 512-thread blocks (8 waves). Waves 0-3 own
// q-tile 2g, waves 4-7 own 2g+1; K/V staged once per block, shared. Per-wave
// depth-2 pipeline: S[kt]; exp/pack/PV[kt-1]; wave-local lgkm P round trip.
// ---------------------------------------------------------------------------
__global__ __launch_bounds__(512)
void attn_fused(const bf16* __restrict__ Qh, const bf16* __restrict__ Kt,
                const bf16* __restrict__ Vt, const int* __restrict__ lengths,
                bf16* __restrict__ out) {
    __shared__ bf16 k_buf[2 * 4096];   // dbuf K tiles  (16 KB)
    __shared__ bf16 v_buf[2 * 4096];   // dbuf V tiles  (16 KB)
    __shared__ bf16 lds_p[8 * 16 * 72];// per-wave P regions (18 KB)

    const int t = threadIdx.x, wave = t >> 6, lane = t & 63;
    const int quad = lane >> 4, l16 = lane & 15;
    const int grp = wave >> 2;          // 0 -> qb=2g, 1 -> qb=2g+1
    const int wq = wave & 3;            // wave-in-group -> 16-row band

    const int bid = blockIdx.x;
    const int xcd = bid & 7;
    int g, bh;
    if (bid < 256) {
        int r = bid >> 3;               // 0..31
        bh = xcd * 4 + (r & 3);
        g = r >> 2;                     // 0..7
    } else {
        int r = (bid - 256) >> 3;
        bh = xcd * 4 + (r & 3);
        g = 15 - (r >> 2);              // 15..8
    }
    const int qb = 2 * g + grp;
    const int b = bh >> 4, h = bh & 15;

    const size_t hb = (size_t)bh * S_ * 64;          // Qh base
    const bf16* Ktp = Kt + (size_t)bh * 32 * 4096;   // tile array base
    const bf16* Vtp = Vt + (size_t)bh * 32 * 4096;
    const int wuni = __builtin_amdgcn_readfirstlane(wave);
    int len_raw = lengths[b];
    const int len_b = len_raw < 1 ? 1 : (len_raw > S_ ? S_ : len_raw);
    const int nkt_len = (len_b + 63) >> 6;

    const int nkt_w = (qb + 1) < nkt_len ? (qb + 1) : nkt_len;      // wave span
    const int nkt   = (2 * g + 2) < nkt_len ? (2 * g + 2) : nkt_len;// block span

    const int qrow_g = qb * 64 + wq * 16 + l16;      // this lane's q-row
    const int kmax = (qrow_g < len_b - 1) ? qrow_g : (len_b - 1);

    s8v qf[2];
    {
        const bf16* qptr = Qh + hb + (size_t)qrow_g * 64 + quad * 8;
        qf[0] = *reinterpret_cast<const s8v*>(qptr);
        qf[1] = *reinterpret_cast<const s8v*>(qptr + 32);
    }

    f4v o_acc[4];
    #pragma unroll
    for (int a = 0; a < 4; a++) o_acc[a] = f4v{0.f, 0.f, 0.f, 0.f};
    float l_sum = 0.f;

    auto stageK = [&](int x) {
        gload_lds16(Ktp + (size_t)x * 4096 + t * 8,
                    (char*)k_buf + (x & 1) * 8192 + wuni * 1024);
    };
    auto stageV = [&](int x) {
        gload_lds16(Vtp + (size_t)x * 4096 + t * 8,
                    (char*)v_buf + (x & 1) * 8192 + wuni * 1024);
    };

    f4v s_prev[4];
    auto process_tile = [&](int pt) {
        const bf16* vb = v_buf + (pt & 1) * 4096;
        const int pbase = pt * 64;
        const bool tail = (pt == qb) || (pbase + 64 > len_b);  // wave-uniform
        #pragma unroll
        for (int a = 0; a < 4; a++) {
            float e0[4];
            #pragma unroll
            for (int r = 0; r < 4; r++) {
                float e = __builtin_amdgcn_exp2f(s_prev[a][r]);
                if (tail) {
                    int key = pbase + a * 16 + quad * 4 + r;
                    e = (key <= kmax) ? e : 0.f;
                }
                e0[r] = e;
                l_sum += e;
            }
            *reinterpret_cast<int2*>(
                &lds_p[(wave * 16 + l16) * 72 + a * 16 + quad * 4]) =
                pack4bf(e0[0], e0[1], e0[2], e0[3]);
        }
        asm volatile("s_waitcnt lgkmcnt(0)" ::: "memory");
        #pragma unroll
        for (int kk = 0; kk < 2; kk++) {
            s8v pf = *reinterpret_cast<const s8v*>(
                &lds_p[(wave * 16 + l16) * 72 + kk * 32 + quad * 8]);
            #pragma unroll
            for (int a = 0; a < 4; a++) {
                int ch = (kk * 4 + quad) ^ (l16 & 7);
                s8v vf = *reinterpret_cast<const s8v*>(
                    &vb[(a * 16 + l16) * 64 + ch * 8]);
                o_acc[a] = mfma_bf16(vf, pf, o_acc[a]);
            }
        }
    };

    stageK(0);
    __syncthreads();   // K[0] resident (drains vmcnt)

    for (int kt = 0; kt < nkt; kt++) {
        stageV(kt);
        if (kt + 1 < nkt) stageK(kt + 1);

        const bool act = (kt < nkt_w);
        f4v sn[4];
        if (act) {
            const bf16* kb = k_buf + (kt & 1) * 4096;
            #pragma unroll
            for (int a = 0; a < 4; a++) sn[a] = f4v{0.f, 0.f, 0.f, 0.f};
            #pragma unroll
            for (int kk = 0; kk < 2; kk++) {
                #pragma unroll
                for (int a = 0; a < 4; a++) {
                    int ch = (kk * 4 + quad) ^ (l16 & 7);
                    s8v kf = *reinterpret_cast<const s8v*>(
                        &kb[(a * 16 + l16) * 64 + ch * 8]);
                    sn[a] = mfma_bf16(kf, qf[kk], sn[a]);
                }
            }
        }

        if (kt >= 1 && (kt - 1) < nkt_w) process_tile(kt - 1);

        if (act) {
            #pragma unroll
            for (int a = 0; a < 4; a++) s_prev[a] = sn[a];
        }

        __syncthreads();   // staged tiles resident; slot reads complete
    }
    if (nkt_w == nkt) process_tile(nkt_w - 1);

    l_sum += __shfl_xor(l_sum, 16);
    l_sum += __shfl_xor(l_sum, 32);
    float inv_l = 1.f / l_sum;
    size_t orow = ((size_t)(b * S_ + qrow_g)) * TD_ + h * 64;
    #pragma unroll
    for (int a = 0; a < 4; a++) {
        *reinterpret_cast<int2*>(&out[orow + a * 16 + quad * 4]) =
            pack4bf(o_acc[a][0] * inv_l, o_acc[a][1] * inv_l,
                    o_acc[a][2] * inv_l, o_acc[a][3] * inv_l);
    }
}

// ---------------------------------------------------------------------------
extern "C" void kernel_launch(void* const* d_in, const int* in_sizes, int n_in,
                              void* d_out, int out_size, void* d_ws, size_t ws_size,
                              hipStream_t stream) {
    const void* query = d_in[0];   // [B,S,DM]  fp32 (auto-detected, bf16-safe)
    const void* W_in  = d_in[1];   // [3TD,DM]
    const void* W_out = d_in[2];   // [DM,TD]
    const void* sin_q = d_in[3];   // [S,HD]
    const void* cos_q = d_in[4];   // [S,HD]   dtype probe
    const void* mask  = d_in[5];   // [B,S] bool, storage auto-detected
    const unsigned int* cosw = (const unsigned int*)cos_q;

    const size_t nQ  = NQ_;   // 4194304
    const size_t nWi = NWI_;  // 3145728
    const size_t nWo = NWO_;  // 1048576

    bf16* Vtmp = (bf16*)d_ws;                 // [4096,1024]; later attn out
    bf16* Qh   = Vtmp + nQ;
    bf16* Kt   = Qh + nQ;                     // tiled+swizzled K
    bf16* qbf  = Kt + nQ;                     // query bf16; later Vt tiles
    bf16* wibf = qbf + nQ;
    bf16* wobf = wibf + nWi;
    bf16* cosb = wobf + nWo;                  // [S][32] bf16
    bf16* sinb = cosb + (size_t)S_ * 32;
    int* lengths = (int*)(sinb + (size_t)S_ * 32);
    bf16* Vt   = qbf;    // alias: qbf dead after gemm1
    bf16* attn = Vtmp;   // alias: Vtmp dead after v_transpose

    prep_all<<<NCVT_BLOCKS + NTAB_BLOCKS + B_, 256, 0, stream>>>(
        query, W_in, W_out, qbf, sin_q, cos_q, cosb, sinb, mask, lengths);

    // gemm1 with fused RoPE epilogue: writes Qh, Kt (swizzled), Vtmp
    dim3 g1(3072 / 128, 4096 / 128);
    gemm_nt<<<g1, 256, 0, stream>>>(qbf, wibf, nullptr, 4096, 3072, 1024, 2,
                                    cosb, sinb, Qh, Kt, Vtmp, cosw);

    v_transpose<<<1024, 256, 0, stream>>>(Vtmp, Vt);

    attn_fused<<<512, 512, 0, stream>>>(Qh, Kt, Vt, lengths, attn);

    dim3 g2(1024 / 128, 4096 / 128);
    gemm_nt<<<g2, 256, 0, stream>>>(attn, wobf, d_out, 4096, 1024, 1024, 1,
                                    nullptr, nullptr, nullptr, nullptr, nullptr, cosw);
}